// Round 6
// baseline (171.302 us; speedup 1.0000x reference)
//
#include <hip/hip_runtime.h>
#include <string.h>

// Integer-quantized MHA. Phase 1: exact-int i8 K=64 MFMA digit GEMM, TRANSPOSED
// (C[s][t] via mfma(K,Q)) so the S-axis quant group is lane-local. Phase 2:
// native bf16 MFMA (r_q<=255, vt mantissa 8-bit -> exact products).
// R12 vs R11 (152.8us total, mha=62.6us, L2 traffic ~1GB ~= 30us floor):
//  - TT=32 via 8 WAVES (512 thr), each wave owns ONE s-tile column (n=w).
//    Per-thread state unchanged vs R11 (64 score elems, scv[2][8][4]=64 regs vs
//    R9's spilling scv[2][16][4]=128): every kd/vd load feeds 32 t-rows ->
//    L2 traffic halves to 512MB (~15us floor). Work totals conserved.
//  - __launch_bounds__(512,2): VGPR cap 256 guarantees block residency;
//    est. peak ~160 regs, no spill (R3's failure mode: watch WRITE_SIZE).
//  - rbuf 32 rows, padded linear layout kept (R11-validated conflict-free);
//    softmax/requant identical math, one extra LDS stage (8 wave-partials).
// B=2,H=16 (BH=32), T=S=1024, HC=128, G=8. Output int32.

typedef int   v4i __attribute__((ext_vector_type(4)));
typedef float v4f __attribute__((ext_vector_type(4)));
typedef short v8s __attribute__((ext_vector_type(8)));
typedef unsigned v2u __attribute__((ext_vector_type(2)));

#define BHN 32
#define TN  1024
#define SN  1024
#define HCN 128
#define TT  32
#define RST 1032               // rbuf row stride (u16): 2064 B == 16 mod 128 -> conflict-free linear
#define KD_BH 262144           // 8 chunks * 32 KB (2 planes, fragment-ordered)
#define VD_BH 262144           // 32 kb * 8 n * 64 lanes * 16 B (bf16 frags)
#define WS_NEED ((size_t)BHN*(KD_BH+VD_BH))   // 16 MB

__device__ __forceinline__ unsigned pack_b(int b0,int b1,int b2,int b3){
    return (unsigned)((b0&255)|((b1&255)<<8)|((b2&255)<<16)|((b3&255)<<24));
}

// digitize 16 consecutive dequantized ints (2 scale groups) into hi/lo i8 digit vectors
__device__ __forceinline__ void dig16(const int* __restrict__ p, int s0, int s1,
                                      v4i& hi, v4i& lo){
    #pragma unroll
    for (int wi=0; wi<4; ++wi){
        v4i m = *(const v4i*)(p + wi*4);
        int s = (wi<2) ? s0 : s1;
        int d0=m[0]<<s, d1=m[1]<<s, d2=m[2]<<s, d3=m[3]<<s;
        hi[wi] = (int)pack_b(d0>>4,d1>>4,d2>>4,d3>>4);
        lo[wi] = (int)pack_b(d0&15,d1&15,d2&15,d3&15);
    }
}

__device__ __forceinline__ unsigned short bf16_of_int(int v){
    return (unsigned short)(__float_as_uint((float)v) >> 16);   // exact: <=8 sig bits
}

// ---------------- pre-pass (gather form: coalesced stores) ----------------
// kd: per bh, [ch(8)][n(8)][kc(2)][plane(2:hi,lo)][lane64][16B]
// vd: per bh, [kb(32)][n(8)][lane64][16B]  (8 bf16 per lane)
// One wave per fragment tile: wave stores lane*16 -> contiguous 1KB per store.
// Tasks: 0..4095 = kd (bh*128+ch*16+n*2+kc); 4096..12287 = vd (bh*256+kb*8+n).
__global__ __launch_bounds__(256) void digitize(
    const int* __restrict__ k_q, const int* __restrict__ k_s,
    const int* __restrict__ vt_q, const int* __restrict__ vt_s,
    unsigned char* __restrict__ kd, unsigned char* __restrict__ vd)
{
    const int w    = threadIdx.x >> 6;
    const int lane = threadIdx.x & 63;
    const int l15  = lane & 15;
    const int task = blockIdx.x*4 + w;
    if (task < 4096){
        const int kc = task & 1, n = (task>>1)&7, ch = (task>>4)&7, bh = task>>7;
        const int q4   = lane >> 4;
        const int srow = bh*SN + ch*128 + n*16 + l15;
        const int gb   = srow*16 + kc*8 + q4*2;
        v4i hi, lo;
        dig16(k_q + (size_t)srow*HCN + kc*64 + q4*16, k_s[gb], k_s[gb+1], hi, lo);
        size_t base = (size_t)bh*KD_BH + (size_t)(ch*32768 + n*4096 + kc*2048 + lane*16);
        *(v4i*)(kd + base)        = hi;     // 1KB coalesced wave store (hi plane)
        *(v4i*)(kd + base + 1024) = lo;     // 1KB coalesced wave store (lo plane)
    } else {
        const int t  = task - 4096;
        const int n  = t & 7, kb = (t>>3)&31, bh = t>>8;
        const int sub = lane >> 4;                 // s-quad within fragment
        const int row = bh*HCN + n*16 + l15;       // vt channel row
        const int* vp = vt_q + (size_t)row*SN + kb*32 + sub*8;
        const int s   = vt_s[row*128 + kb*4 + sub];
        unsigned wds[4];
        #pragma unroll
        for (int j=0;j<4;j++){
            int a = vp[j*2]   << s;
            int b = vp[j*2+1] << s;
            wds[j] = (unsigned)bf16_of_int(a) | ((unsigned)bf16_of_int(b) << 16);
        }
        size_t base = (size_t)bh*VD_BH + (size_t)(((kb*8 + n)*64 + lane)*16);
        *(v4i*)(vd + base) = v4i{(int)wds[0],(int)wds[1],(int)wds[2],(int)wds[3]};
    }
}

// ---------------- main fused kernel ----------------
// 512 threads = 8 waves. Wave w owns s-tile column n=w in phase 1 and channel
// group n=w in phase 2. Block covers 32 t-rows (two 16-row halves h=0,1).
template<bool PK>
__global__ __launch_bounds__(512,2) void mha_mfma(
    const int* __restrict__ q_q, const int* __restrict__ q_s,
    const int* __restrict__ k_q, const int* __restrict__ k_s,
    const int* __restrict__ vt_q, const int* __restrict__ vt_s,
    const unsigned char* __restrict__ kd, const unsigned char* __restrict__ vd,
    int* __restrict__ out)
{
    __shared__ __align__(16) unsigned short rbuf[32*RST];   // 66 KB r values (bf16), linear
    __shared__ int   redi[256];                             // [h][w][ln] int max partials
    __shared__ float redf[256];                             // [h][w][ln] sum partials

    const int tid  = threadIdx.x;
    const int ln   = tid & 15;
    const int qd4  = (tid >> 4) & 3;
    const int w    = tid >> 6;          // 0..7
    const int lane = tid & 63;
    // XCD-aware swizzle: each XCD's share covers only 4 bh -> digit images fit its L2.
    const int blk = blockIdx.x;                 // 1024 blocks
    const int bh  = ((blk>>8)<<3) | (blk&7);    // 32 bh
    const int t0  = ((blk>>3)&31) * TT;         // 32 t-tiles of 32

    // ---- Q fragments in registers for both halves (B operand in phase 1, t=ln) ----
    v4i qfh[2][2], qfl[2][2];          // [h][kc]
    #pragma unroll
    for (int h=0; h<2; ++h){
        const int* qrow  = q_q + (size_t)(bh*TN + t0 + h*16 + ln)*HCN;
        const int* qsrow = q_s + (size_t)(bh*TN + t0 + h*16 + ln)*16;
        #pragma unroll
        for (int kc=0; kc<2; ++kc){
            int gi = kc*8 + qd4*2;
            dig16(qrow + kc*64 + qd4*16, qsrow[gi], qsrow[gi+1], qfh[h][kc], qfl[h][kc]);
        }
    }

    int scv[2][8][4];   // C[s][t]: s = (ch*8 + w)*16 + qd4*4 + r, t = h*16 + ln

    // ========== phase 1: QK^T scores, transposed (barrier-free, exact int) ==========
    // Each kd load feeds BOTH t-halves: L2 traffic per output row halved vs TT=16.
    const v4i* kb_ = (const v4i*)(kd + (size_t)bh*KD_BH);
    #pragma unroll
    for (int ch=0; ch<8; ++ch){
        v4i a2[2]={{0,0,0,0},{0,0,0,0}}, a1[2]={{0,0,0,0},{0,0,0,0}},
            a0[2]={{0,0,0,0},{0,0,0,0}};
        #pragma unroll
        for (int kc=0;kc<2;kc++){
            v4i bhv, blv;
            if (PK){
                const v4i* tb = kb_ + (ch*8+w)*256 + kc*128 + lane;
                bhv = tb[0];
                blv = tb[64];
            } else {
                int srow = bh*SN + ch*128 + w*16 + ln;
                int cc   = kc*64 + qd4*16;
                dig16(k_q + (size_t)srow*128 + cc,
                      k_s[srow*16 + (cc>>3)], k_s[srow*16 + (cc>>3) + 1], bhv, blv);
            }
            // A = K digits, B = Q digits  ->  C[s][t]
            #pragma unroll
            for (int h=0;h<2;h++){
                a2[h] = __builtin_amdgcn_mfma_i32_16x16x64_i8(bhv, qfh[h][kc], a2[h], 0,0,0);
                a1[h] = __builtin_amdgcn_mfma_i32_16x16x64_i8(bhv, qfl[h][kc], a1[h], 0,0,0);
                a1[h] = __builtin_amdgcn_mfma_i32_16x16x64_i8(blv, qfh[h][kc], a1[h], 0,0,0);
                a0[h] = __builtin_amdgcn_mfma_i32_16x16x64_i8(blv, qfl[h][kc], a0[h], 0,0,0);
            }
        }
        #pragma unroll
        for (int h=0;h<2;h++)
            #pragma unroll
            for (int r=0;r<4;r++)
                scv[h][ch][r] = (a2[h][r]<<8) + (a1[h][r]<<4) + a0[h][r];
    }

    // ================= softmax over s (int-domain max, log2-domain exp) =================
    // Thread's 32 elements per half belong to ONE output row t = h*16 + ln.
    const float CS2 = (float)(6.103515625e-05 / 11.313708498984760390566
                              * 1.4426950408889634074);
    #pragma unroll
    for (int h=0;h<2;h++){
        int m0=-2147483647, m1=-2147483647, m2=-2147483647, m3=-2147483647;
        #pragma unroll
        for (int ch=0;ch<8;ch++){
            m0 = max(m0, scv[h][ch][0]);
            m1 = max(m1, scv[h][ch][1]);
            m2 = max(m2, scv[h][ch][2]);
            m3 = max(m3, scv[h][ch][3]);
        }
        int m_ = max(max(m0,m1), max(m2,m3));
        m_ = max(m_, __shfl_xor(m_, 16));
        m_ = max(m_, __shfl_xor(m_, 32));
        if (qd4 == 0) redi[h*128 + w*16 + ln] = m_;
    }
    __syncthreads();
    #pragma unroll
    for (int h=0;h<2;h++){
        int mr = redi[h*128 + ln];
        #pragma unroll
        for (int w2=1;w2<8;w2++) mr = max(mr, redi[h*128 + w2*16 + ln]);
        float s0=0.f, s1=0.f, s2=0.f, s3=0.f;
        #pragma unroll
        for (int ch=0;ch<8;ch++){
            #pragma unroll
            for (int r=0;r<4;r++){
                float t_ = (float)(scv[h][ch][r] - mr) * CS2;   // <= 0, diff exact in i32
                float e;
                asm("v_exp_f32 %0, %1" : "=v"(e) : "v"(t_));    // 2^t
                scv[h][ch][r] = __float_as_int(e);
                if (r==0) s0 += e; else if (r==1) s1 += e; else if (r==2) s2 += e; else s3 += e;
            }
        }
        float s_ = (s0+s1) + (s2+s3);
        s_ += __shfl_xor(s_, 16);
        s_ += __shfl_xor(s_, 32);
        if (qd4 == 0) redf[h*128 + w*16 + ln] = s_;
    }
    __syncthreads();
    float inv14[2];
    #pragma unroll
    for (int h=0;h<2;h++){
        float sum = 0.f;
        #pragma unroll
        for (int w2=0;w2<8;w2++) sum += redf[h*128 + w2*16 + ln];
        inv14[h] = 16384.0f / sum;     // one IEEE div per row-half
    }

    // ======== group-of-8 po2 requant, in registers -> b64 rbuf stores ========
    // granule = thread's 4 s-values + partner at lane^16; gmax <= 255<<sh so no clamp.
    // Linear store at padded stride: bank-pair (4ln+8w+2qd4)&31 hit by exactly
    // 2 lanes (ln, ln+8) per wave-store = free 2-way. No swizzle arithmetic.
    #pragma unroll
    for (int h=0;h<2;h++){
        unsigned short* rp = rbuf + (h*16 + ln)*RST;
        #pragma unroll
        for (int ch=0;ch<8;ch++){
            float v0 = rintf(__int_as_float(scv[h][ch][0]) * inv14[h]);
            float v1 = rintf(__int_as_float(scv[h][ch][1]) * inv14[h]);
            float v2 = rintf(__int_as_float(scv[h][ch][2]) * inv14[h]);
            float v3 = rintf(__int_as_float(scv[h][ch][3]) * inv14[h]);
            float g = fmaxf(fmaxf(v0,v1), fmaxf(v2,v3));
            g = fmaxf(g, __shfl_xor(g, 16));            // partner half of the granule
            int gi = max((int)g, 1);
            int x  = gi - 1;
            int e2 = 31 - __clz(x | 255);
            int sh = (e2 - 7) + ((x >> (e2 - 7)) == 255); // clip(ceil(log2(gi/255)),0,)
            float isc = __int_as_float((127 - sh) << 23); // exact 2^-sh
            float fsc = __int_as_float((127 + sh) << 23); // exact 2^sh
            unsigned b0 = __float_as_uint(rintf(v0*isc) * fsc);  // r = rq<<sh, 8 sig bits
            unsigned b1 = __float_as_uint(rintf(v1*isc) * fsc);
            unsigned b2 = __float_as_uint(rintf(v2*isc) * fsc);
            unsigned b3 = __float_as_uint(rintf(v3*isc) * fsc);
            unsigned w0 = __builtin_amdgcn_perm(b1, b0, 0x07060302u); // {bf16(v0),bf16(v1)}
            unsigned w1 = __builtin_amdgcn_perm(b3, b2, 0x07060302u);
            int c0 = (ch*8 + w)*16 + qd4*4;             // col of v0 (u16 units, 4-aligned)
            *(v2u*)(rp + c0) = v2u{w0, w1};             // one linear b64 store per tile
        }
    }
    __syncthreads();

    // ========= phase 2: out = r @ vt^T (bf16 MFMA; each vd load feeds both halves) =========
    // Linear b128 read at padded stride: bank group = (ln + kb*4 + qd4)&7 ->
    // 8 accesses/bank per wave-read (minimum for 1KB). No swizzle.
    const v4i* vb = (const v4i*)(vd + (size_t)bh*VD_BH);
    const unsigned short* rp0 = rbuf + ln*RST;
    const unsigned short* rp1 = rbuf + (16 + ln)*RST;
    v4f acc0{0,0,0,0}, acc1{0,0,0,0};
    #pragma unroll 4
    for (int kb=0; kb<32; ++kb){
        // A frags: r[t][s = kb*32 + qd4*8 + j], 8 bf16 = one b128 from LDS per half
        v8s af0 = *(const v8s*)(rp0 + kb*32 + qd4*8);
        v8s af1 = *(const v8s*)(rp1 + kb*32 + qd4*8);
        v4i b0;
        if (PK){
            b0 = vb[(kb*8 + w)*64 + lane];
        } else {
            int chan = w*16 + ln;
            const int* vp = vt_q + (size_t)(bh*HCN + chan)*SN + kb*32 + qd4*8;
            int s = vt_s[(bh*HCN + chan)*128 + kb*4 + qd4];
            unsigned wd[4];
            #pragma unroll
            for (int j=0;j<4;j++){
                int a = vp[j*2]   << s;
                int b = vp[j*2+1] << s;
                wd[j] = (unsigned)bf16_of_int(a) | ((unsigned)bf16_of_int(b)<<16);
            }
            b0 = v4i{(int)wd[0],(int)wd[1],(int)wd[2],(int)wd[3]};
        }
        v8s bs0;
        memcpy(&bs0, &b0, 16);
        acc0 = __builtin_amdgcn_mfma_f32_16x16x32_bf16(af0, bs0, acc0, 0,0,0);
        acc1 = __builtin_amdgcn_mfma_f32_16x16x32_bf16(af1, bs0, acc1, 0,0,0);
    }
    #pragma unroll
    for (int r=0;r<4;r++){
        size_t o0 = (size_t)(bh*TN + t0 + qd4*4 + r)*HCN + w*16 + ln;
        out[o0] = (int)rintf(acc0[r]);
        out[o0 + (size_t)16*HCN] = (int)rintf(acc1[r]);   // h=1 rows t0+16..
    }
}

extern "C" void kernel_launch(void* const* d_in, const int* in_sizes, int n_in,
                              void* d_out, int out_size, void* d_ws, size_t ws_size,
                              hipStream_t stream) {
    const int* q_q  = (const int*)d_in[0];
    const int* q_s  = (const int*)d_in[1];
    const int* k_q  = (const int*)d_in[2];
    const int* k_s  = (const int*)d_in[3];
    const int* vt_q = (const int*)d_in[4];
    const int* vt_s = (const int*)d_in[5];
    int* out = (int*)d_out;

    unsigned char* kd = (unsigned char*)d_ws;
    unsigned char* vd = kd + (size_t)BHN*KD_BH;

    if (ws_size >= WS_NEED){
        // 12288 wave-tasks (4096 kd + 8192 vd), 4 waves/block
        digitize<<<dim3(3072), 256, 0, stream>>>(k_q,k_s,vt_q,vt_s, kd,vd);
        mha_mfma<true><<<dim3(1024), 512, 0, stream>>>(
            q_q,q_s,k_q,k_s,vt_q,vt_s, kd,vd, out);
    } else {
        mha_mfma<false><<<dim3(1024), 512, 0, stream>>>(
            q_q,q_s,k_q,k_s,vt_q,vt_s, kd,vd, out);
    }
}

// Round 7
// 152.142 us; speedup vs baseline: 1.1259x; 1.1259x over previous
//
#include <hip/hip_runtime.h>
#include <string.h>

// Integer-quantized MHA. Phase 1: exact-int i8 K=64 MFMA digit GEMM, TRANSPOSED
// (C[s][t] via mfma(K,Q)) so the S-axis quant group is lane-local. Phase 2:
// native bf16 MFMA (r_q<=255, vt mantissa 8-bit -> exact products).
// R13 vs R12 (171us, mha=79.6us: TT=32/8w -> 1 block/CU, occupancy 21%) and
// R11 (152.8us, mha=62.6us, 3 blocks/CU):
//  - TT=32 axis CLOSED (R9 spill, R12 occupancy). Back to R11 structure.
//  - Evidence from R11 (33.8KB->3 blocks) + R12 (68KB->1 block) => usable
//    LDS/CU ~= 128KB. This round: LDS block = EXACTLY 32768B -> 4 blocks/CU
//    (16 waves), +33% latency hiding for a latency-bound phase mix.
//    * rbuf unpadded 16x1024 u16 = 32KB.
//    * XOR col swizzle c^=((ln&7)<<4) on requant store + phase-2 read
//      (bank-minimal both sides: store 4/bank, read 8/bank; bijective,
//      8-aligned runs stay contiguous -- unlike R10's additive rotation).
//    * red/redi carved into rbuf row 15 cols 768..1023 (dead until requant);
//      one extra barrier between sum-read and requant stores.
//  - All arithmetic bit-identical to R11.
// B=2,H=16 (BH=32), T=S=1024, HC=128, G=8. Output int32.

typedef int   v4i __attribute__((ext_vector_type(4)));
typedef float v4f __attribute__((ext_vector_type(4)));
typedef short v8s __attribute__((ext_vector_type(8)));
typedef unsigned v2u __attribute__((ext_vector_type(2)));

#define BHN 32
#define TN  1024
#define SN  1024
#define HCN 128
#define TT  16
#define KD_BH 262144           // 8 chunks * 32 KB (2 planes, fragment-ordered)
#define VD_BH 262144           // 32 kb * 8 n * 64 lanes * 16 B (bf16 frags)
#define WS_NEED ((size_t)BHN*(KD_BH+VD_BH))   // 16 MB

__device__ __forceinline__ unsigned pack_b(int b0,int b1,int b2,int b3){
    return (unsigned)((b0&255)|((b1&255)<<8)|((b2&255)<<16)|((b3&255)<<24));
}

// digitize 16 consecutive dequantized ints (2 scale groups) into hi/lo i8 digit vectors
__device__ __forceinline__ void dig16(const int* __restrict__ p, int s0, int s1,
                                      v4i& hi, v4i& lo){
    #pragma unroll
    for (int wi=0; wi<4; ++wi){
        v4i m = *(const v4i*)(p + wi*4);
        int s = (wi<2) ? s0 : s1;
        int d0=m[0]<<s, d1=m[1]<<s, d2=m[2]<<s, d3=m[3]<<s;
        hi[wi] = (int)pack_b(d0>>4,d1>>4,d2>>4,d3>>4);
        lo[wi] = (int)pack_b(d0&15,d1&15,d2&15,d3&15);
    }
}

__device__ __forceinline__ unsigned short bf16_of_int(int v){
    return (unsigned short)(__float_as_uint((float)v) >> 16);   // exact: <=8 sig bits
}

// ---------------- pre-pass (gather form: coalesced stores) ----------------
// kd: per bh, [ch(8)][n(8)][kc(2)][plane(2:hi,lo)][lane64][16B]
// vd: per bh, [kb(32)][n(8)][lane64][16B]  (8 bf16 per lane)
// One wave per fragment tile: wave stores lane*16 -> contiguous 1KB per store.
// Tasks: 0..4095 = kd (bh*128+ch*16+n*2+kc); 4096..12287 = vd (bh*256+kb*8+n).
__global__ __launch_bounds__(256) void digitize(
    const int* __restrict__ k_q, const int* __restrict__ k_s,
    const int* __restrict__ vt_q, const int* __restrict__ vt_s,
    unsigned char* __restrict__ kd, unsigned char* __restrict__ vd)
{
    const int w    = threadIdx.x >> 6;
    const int lane = threadIdx.x & 63;
    const int l15  = lane & 15;
    const int task = blockIdx.x*4 + w;
    if (task < 4096){
        const int kc = task & 1, n = (task>>1)&7, ch = (task>>4)&7, bh = task>>7;
        const int q4   = lane >> 4;
        const int srow = bh*SN + ch*128 + n*16 + l15;
        const int gb   = srow*16 + kc*8 + q4*2;
        v4i hi, lo;
        dig16(k_q + (size_t)srow*HCN + kc*64 + q4*16, k_s[gb], k_s[gb+1], hi, lo);
        size_t base = (size_t)bh*KD_BH + (size_t)(ch*32768 + n*4096 + kc*2048 + lane*16);
        *(v4i*)(kd + base)        = hi;     // 1KB coalesced wave store (hi plane)
        *(v4i*)(kd + base + 1024) = lo;     // 1KB coalesced wave store (lo plane)
    } else {
        const int t  = task - 4096;
        const int n  = t & 7, kb = (t>>3)&31, bh = t>>8;
        const int sub = lane >> 4;                 // s-quad within fragment
        const int row = bh*HCN + n*16 + l15;       // vt channel row
        const int* vp = vt_q + (size_t)row*SN + kb*32 + sub*8;
        const int s   = vt_s[row*128 + kb*4 + sub];
        unsigned wds[4];
        #pragma unroll
        for (int j=0;j<4;j++){
            int a = vp[j*2]   << s;
            int b = vp[j*2+1] << s;
            wds[j] = (unsigned)bf16_of_int(a) | ((unsigned)bf16_of_int(b) << 16);
        }
        size_t base = (size_t)bh*VD_BH + (size_t)(((kb*8 + n)*64 + lane)*16);
        *(v4i*)(vd + base) = v4i{(int)wds[0],(int)wds[1],(int)wds[2],(int)wds[3]};
    }
}

// ---------------- main fused kernel ----------------
template<bool PK>
__global__ __launch_bounds__(256,4) void mha_mfma(
    const int* __restrict__ q_q, const int* __restrict__ q_s,
    const int* __restrict__ k_q, const int* __restrict__ k_s,
    const int* __restrict__ vt_q, const int* __restrict__ vt_s,
    const unsigned char* __restrict__ kd, const unsigned char* __restrict__ vd,
    int* __restrict__ out)
{
    // EXACTLY 32 KB: 4 blocks/CU under the 128KB-usable-LDS hypothesis.
    __shared__ __align__(16) unsigned short rbuf[16*1024];
    // reduction scratch carved into rbuf (row 15, cols 768..1023) -- this
    // region is only written by requant AFTER the barrier that follows the
    // sum-read, so the aliasing is safe.
    int*   redi = (int*)  (rbuf + 16128);   // 64 ints   (row15 cols 768..895)
    float* redf = (float*)(rbuf + 16256);   // 64 floats (row15 cols 896..1023)

    const int tid  = threadIdx.x;
    const int ln   = tid & 15;
    const int qd4  = (tid >> 4) & 3;
    const int w    = tid >> 6;
    const int lane = tid & 63;
    // XCD-aware swizzle: each XCD's share covers only 4 bh -> digit images fit its L2.
    const int blk = blockIdx.x;
    const int bh  = ((blk>>9)<<3) | (blk&7);
    const int t0  = ((blk>>3)&63) * TT;

    // ---- Q fragments in registers (B operand in phase 1, t=ln) ----
    v4i qfh[2], qfl[2];
    {
        const int* qrow  = q_q + (size_t)(bh*TN + t0 + ln)*HCN;
        const int* qsrow = q_s + (size_t)(bh*TN + t0 + ln)*16;
        #pragma unroll
        for (int kc=0; kc<2; ++kc){
            int gi = kc*8 + qd4*2;
            dig16(qrow + kc*64 + qd4*16, qsrow[gi], qsrow[gi+1], qfh[kc], qfl[kc]);
        }
    }

    int scv[16][4];   // C[s][t]: s = (ch*8 + w*2 + i)*16 + qd4*4 + r, t = ln

    // ========== phase 1: QK^T scores, transposed (barrier-free, exact int) ==========
    const v4i* kb_ = (const v4i*)(kd + (size_t)bh*KD_BH);
    for (int ch=0; ch<8; ++ch){
        #pragma unroll
        for (int i=0;i<2;i++){
            const int n = w*2 + i;
            v4i a2{0,0,0,0}, a1{0,0,0,0}, a0{0,0,0,0};
            #pragma unroll
            for (int kc=0;kc<2;kc++){
                v4i bhv, blv;
                if (PK){
                    const v4i* tb = kb_ + (ch*8+n)*256 + kc*128 + lane;
                    bhv = tb[0];
                    blv = tb[64];
                } else {
                    int srow = bh*SN + ch*128 + n*16 + ln;
                    int cc   = kc*64 + qd4*16;
                    dig16(k_q + (size_t)srow*128 + cc,
                          k_s[srow*16 + (cc>>3)], k_s[srow*16 + (cc>>3) + 1], bhv, blv);
                }
                // A = K digits, B = Q digits  ->  C[s][t]
                a2 = __builtin_amdgcn_mfma_i32_16x16x64_i8(bhv, qfh[kc], a2, 0,0,0);
                a1 = __builtin_amdgcn_mfma_i32_16x16x64_i8(bhv, qfl[kc], a1, 0,0,0);
                a1 = __builtin_amdgcn_mfma_i32_16x16x64_i8(blv, qfh[kc], a1, 0,0,0);
                a0 = __builtin_amdgcn_mfma_i32_16x16x64_i8(blv, qfl[kc], a0, 0,0,0);
            }
            int st = ch*2 + i;
            #pragma unroll
            for (int r=0;r<4;r++)
                scv[st][r] = (a2[r]<<8) + (a1[r]<<4) + a0[r];
        }
    }

    // ================= softmax over s (int-domain max, log2-domain exp) =================
    // Thread's 64 elements belong to ONE output row t=ln. Scale is positive ->
    // argmax over raw int scores == argmax over logits (monotone).
    const float CS2 = (float)(6.103515625e-05 / 11.313708498984760390566
                              * 1.4426950408889634074);
    {
        int m0=-2147483647, m1=-2147483647, m2=-2147483647, m3=-2147483647;
        #pragma unroll
        for (int st=0;st<16;st++){
            m0 = max(m0, scv[st][0]);
            m1 = max(m1, scv[st][1]);
            m2 = max(m2, scv[st][2]);
            m3 = max(m3, scv[st][3]);
        }
        int m_ = max(max(m0,m1), max(m2,m3));
        m_ = max(m_, __shfl_xor(m_, 16));
        m_ = max(m_, __shfl_xor(m_, 32));
        if ((tid & 48) == 0) redi[w*16 + ln] = m_;
    }
    __syncthreads();                                  // bar1: redi visible
    float inv14;
    {
        const int mrow = max(max(redi[ln], redi[16+ln]), max(redi[32+ln], redi[48+ln]));
        float s0=0.f, s1=0.f, s2=0.f, s3=0.f;
        #pragma unroll
        for (int st=0;st<16;st++){
            #pragma unroll
            for (int r=0;r<4;r++){
                float t_ = (float)(scv[st][r] - mrow) * CS2;   // <= 0, diff exact in i32
                float e;
                asm("v_exp_f32 %0, %1" : "=v"(e) : "v"(t_));   // 2^t
                scv[st][r] = __float_as_int(e);
                if (r==0) s0 += e; else if (r==1) s1 += e; else if (r==2) s2 += e; else s3 += e;
            }
        }
        float s_ = (s0+s1) + (s2+s3);
        s_ += __shfl_xor(s_, 16);
        s_ += __shfl_xor(s_, 32);
        if ((tid & 48) == 0) redf[w*16 + ln] = s_;    // distinct region from redi
    }
    __syncthreads();                                  // bar2: redf visible
    {
        float sum = redf[ln] + redf[16+ln] + redf[32+ln] + redf[48+ln];
        inv14 = 16384.0f / sum;        // one IEEE div per thread
    }
    __syncthreads();                                  // bar3: all sum-reads done
                                                      // before requant overwrites row 15

    // ======== group-of-8 po2 requant, in registers -> b64 rbuf stores ========
    // granule = thread's 4 s-values + partner at lane^16; gmax <= 255<<sh so no clamp.
    // XOR swizzle c' = c ^ ((ln&7)<<4) on unpadded 2048B rows:
    //   store start-banks {0,qd4_0,qd4_1,st0^l0,w0^l1} -> uniform 4/bank (min);
    //   8-aligned runs stay contiguous (XOR bits >=4), bijective per row.
    {
        const int lnr4 = (ln & 7) << 4;
        const int cbase = w*32 + qd4*4;
        unsigned short* rp = rbuf + ln*1024;
        #pragma unroll
        for (int st=0;st<16;st++){
            float v0 = rintf(__int_as_float(scv[st][0]) * inv14);
            float v1 = rintf(__int_as_float(scv[st][1]) * inv14);
            float v2 = rintf(__int_as_float(scv[st][2]) * inv14);
            float v3 = rintf(__int_as_float(scv[st][3]) * inv14);
            float g = fmaxf(fmaxf(v0,v1), fmaxf(v2,v3));
            g = fmaxf(g, __shfl_xor(g, 16));            // partner half of the granule
            int gi = max((int)g, 1);
            int x  = gi - 1;
            int e2 = 31 - __clz(x | 255);
            int sh = (e2 - 7) + ((x >> (e2 - 7)) == 255); // clip(ceil(log2(gi/255)),0,)
            float isc = __int_as_float((127 - sh) << 23); // exact 2^-sh
            float fsc = __int_as_float((127 + sh) << 23); // exact 2^sh
            unsigned b0 = __float_as_uint(rintf(v0*isc) * fsc);  // r = rq<<sh, 8 sig bits
            unsigned b1 = __float_as_uint(rintf(v1*isc) * fsc);
            unsigned b2 = __float_as_uint(rintf(v2*isc) * fsc);
            unsigned b3 = __float_as_uint(rintf(v3*isc) * fsc);
            unsigned w0 = __builtin_amdgcn_perm(b1, b0, 0x07060302u); // {bf16(v0),bf16(v1)}
            unsigned w1 = __builtin_amdgcn_perm(b3, b2, 0x07060302u);
            int c0 = (st>>1)*128 + cbase + (st&1)*16;   // col of v0 (u16 units, 4-aligned)
            *(v2u*)(rp + (c0 ^ lnr4)) = v2u{w0, w1};    // one swizzled b64 store per tile
        }
    }
    __syncthreads();                                  // bar4: rbuf ready

    // ================= phase 2: out = r @ vt^T (bf16 MFMA, barrier-free) =================
    // b128 read at swizzled col: start-banks {0,0,qd4_0,qd4_1^l0,kb0^l1} ->
    // uniform 8/bank (minimum for 1KB wave-read).
    const v4i* vb = (const v4i*)(vd + (size_t)bh*VD_BH);
    const unsigned short* rp2 = rbuf + ln*1024;
    const int lnr4b = (ln & 7) << 4;
    v4f acc0{0,0,0,0}, acc1{0,0,0,0};
    #pragma unroll 4
    for (int kb=0; kb<32; ++kb){
        // A frag: r[t=ln][s = kb*32 + qd4*8 + j], 8 bf16 = one b128 from LDS
        v8s af = *(const v8s*)(rp2 + ((kb*32 + qd4*8) ^ lnr4b));
        v4i b0, b1;
        if (PK){
            b0 = vb[(kb*8 + w*2    )*64 + lane];
            b1 = vb[(kb*8 + w*2 + 1)*64 + lane];
        } else {
            #pragma unroll
            for (int i=0;i<2;i++){
                int chan = (w*2+i)*16 + ln;
                const int* vp = vt_q + (size_t)(bh*HCN + chan)*SN + kb*32 + qd4*8;
                int s = vt_s[(bh*HCN + chan)*128 + kb*4 + qd4];
                unsigned wd[4];
                #pragma unroll
                for (int j=0;j<4;j++){
                    int a = vp[j*2]   << s;
                    int b = vp[j*2+1] << s;
                    wd[j] = (unsigned)bf16_of_int(a) | ((unsigned)bf16_of_int(b)<<16);
                }
                v4i t{(int)wd[0],(int)wd[1],(int)wd[2],(int)wd[3]};
                if (i==0) b0 = t; else b1 = t;
            }
        }
        v8s bs0, bs1;
        memcpy(&bs0, &b0, 16);
        memcpy(&bs1, &b1, 16);
        acc0 = __builtin_amdgcn_mfma_f32_16x16x32_bf16(af, bs0, acc0, 0,0,0);
        acc1 = __builtin_amdgcn_mfma_f32_16x16x32_bf16(af, bs1, acc1, 0,0,0);
    }
    #pragma unroll
    for (int r=0;r<4;r++){
        size_t o = (size_t)(bh*TN + t0 + qd4*4 + r)*HCN + w*32 + ln;
        out[o]      = (int)rintf(acc0[r]);
        out[o + 16] = (int)rintf(acc1[r]);
    }
}

extern "C" void kernel_launch(void* const* d_in, const int* in_sizes, int n_in,
                              void* d_out, int out_size, void* d_ws, size_t ws_size,
                              hipStream_t stream) {
    const int* q_q  = (const int*)d_in[0];
    const int* q_s  = (const int*)d_in[1];
    const int* k_q  = (const int*)d_in[2];
    const int* k_s  = (const int*)d_in[3];
    const int* vt_q = (const int*)d_in[4];
    const int* vt_s = (const int*)d_in[5];
    int* out = (int*)d_out;

    unsigned char* kd = (unsigned char*)d_ws;
    unsigned char* vd = kd + (size_t)BHN*KD_BH;

    if (ws_size >= WS_NEED){
        // 12288 wave-tasks (4096 kd + 8192 vd), 4 waves/block
        digitize<<<dim3(3072), 256, 0, stream>>>(k_q,k_s,vt_q,vt_s, kd,vd);
        mha_mfma<true><<<dim3(2048), 256, 0, stream>>>(
            q_q,q_s,k_q,k_s,vt_q,vt_s, kd,vd, out);
    } else {
        mha_mfma<false><<<dim3(2048), 256, 0, stream>>>(
            q_q,q_s,k_q,k_s,vt_q,vt_s, kd,vd, out);
    }
}